// Round 1
// baseline (1483.732 us; speedup 1.0000x reference)
//
#include <hip/hip_runtime.h>

#define N_NODES 100000
#define N_EDGES 1600000
#define D 64

// ---------------------------------------------------------------- zero agg
__global__ __launch_bounds__(256) void zero_kernel(float4* __restrict__ p, int n4) {
    int t = blockIdx.x * 256 + threadIdx.x;
    if (t < n4) p[t] = make_float4(0.f, 0.f, 0.f, 0.f);
}

// ---------------------------------------------------------------- edge scatter
// 16 threads per edge, float4 per thread, hardware fp32 atomics.
__global__ __launch_bounds__(256) void scatter_add_kernel(
    const float* __restrict__ x, const int* __restrict__ row,
    const int* __restrict__ col, float* __restrict__ agg)
{
    int t = blockIdx.x * 256 + threadIdx.x;
    int e = t >> 4;
    if (e >= N_EDGES) return;
    int q = (t & 15) << 2;
    int src = row[e];
    int dst = col[e];
    const float4 v = *reinterpret_cast<const float4*>(x + (size_t)src * D + q);
    float* base = agg + (size_t)dst * D + q;
    unsafeAtomicAdd(base + 0, v.x);
    unsafeAtomicAdd(base + 1, v.y);
    unsafeAtomicAdd(base + 2, v.z);
    unsafeAtomicAdd(base + 3, v.w);
}

// ---------------------------------------------------------------- fused norm + dual GEMM + bias + relu
// out[n][j] = relu( sum_d (agg[n][d]/norm[n]) * rel_W[j][d]
//                 + sum_d x[n][d]            * root_W[j][d] + root_b[j] )
// Block = 256 threads, tile = 64 nodes. Two K-phases (rel then root), each
// staging a 64x64 input tile and 64x64 weight tile in LDS (stride 68).
#define STRIDE 68

__global__ __launch_bounds__(256) void fused_out_kernel(
    const float* __restrict__ x, const float* __restrict__ agg,
    const float* __restrict__ adj_norm,
    const float* __restrict__ root_W, const float* __restrict__ root_b,
    const float* __restrict__ rel_W, float* __restrict__ out)
{
    __shared__ float in_sh[64 * STRIDE];
    __shared__ float w_sh[64 * STRIDE];

    const int tid = threadIdx.x;
    const int n0 = blockIdx.x * 64;
    const int jq = tid & 15;   // 16 distinct j-groups per wave -> coalesced stores
    const int nq = tid >> 4;   // 4 distinct per wave -> broadcast LDS reads

    float acc[4][4] = {};      // [i: n = nq+16i][k: j = jq+16k]

    for (int phase = 0; phase < 2; ++phase) {
        const float* __restrict__ W = phase ? root_W : rel_W;

        if (phase) __syncthreads();   // protect previous compute before restage

        // stage weight tile: w_sh[j][d] = W[j*64+d]
        #pragma unroll
        for (int r = 0; r < 4; ++r) {
            int f = r * 256 + tid;       // 0..1023 float4s
            int j = f >> 4;
            int dq = (f & 15) << 2;
            float4 wv = *reinterpret_cast<const float4*>(W + j * 64 + dq);
            *reinterpret_cast<float4*>(&w_sh[j * STRIDE + dq]) = wv;
        }
        // stage input tile: phase 0 -> agg/norm, phase 1 -> x
        #pragma unroll
        for (int r = 0; r < 4; ++r) {
            int f = r * 256 + tid;
            int n = f >> 4;
            int dq = (f & 15) << 2;
            int gn = n0 + n;
            float4 v = make_float4(0.f, 0.f, 0.f, 0.f);
            if (gn < N_NODES) {
                if (phase == 0) {
                    float inv = 1.0f / adj_norm[gn];
                    v = *reinterpret_cast<const float4*>(agg + (size_t)gn * D + dq);
                    v.x *= inv; v.y *= inv; v.z *= inv; v.w *= inv;
                } else {
                    v = *reinterpret_cast<const float4*>(x + (size_t)gn * D + dq);
                }
            }
            *reinterpret_cast<float4*>(&in_sh[n * STRIDE + dq]) = v;
        }
        __syncthreads();

        // 4x4 register-tiled accumulation over this 64-wide K slice
        for (int d = 0; d < 64; d += 4) {
            float4 a[4], w[4];
            #pragma unroll
            for (int i = 0; i < 4; ++i)
                a[i] = *reinterpret_cast<const float4*>(&in_sh[(nq + 16 * i) * STRIDE + d]);
            #pragma unroll
            for (int k = 0; k < 4; ++k)
                w[k] = *reinterpret_cast<const float4*>(&w_sh[(jq + 16 * k) * STRIDE + d]);
            #pragma unroll
            for (int i = 0; i < 4; ++i)
                #pragma unroll
                for (int k = 0; k < 4; ++k)
                    acc[i][k] += a[i].x * w[k].x + a[i].y * w[k].y
                               + a[i].z * w[k].z + a[i].w * w[k].w;
        }
    }

    // epilogue: bias + relu + store (coalesced: 16 consecutive j per quarter-wave)
    #pragma unroll
    for (int i = 0; i < 4; ++i) {
        int gn = n0 + nq + 16 * i;
        if (gn >= N_NODES) continue;
        #pragma unroll
        for (int k = 0; k < 4; ++k) {
            int j = jq + 16 * k;
            float v = acc[i][k] + root_b[j];
            out[(size_t)gn * D + j] = fmaxf(v, 0.0f);
        }
    }
}

// ---------------------------------------------------------------- launch
extern "C" void kernel_launch(void* const* d_in, const int* in_sizes, int n_in,
                              void* d_out, int out_size, void* d_ws, size_t ws_size,
                              hipStream_t stream)
{
    const float* x        = (const float*)d_in[0];
    const int*   row      = (const int*)d_in[1];
    const int*   col      = (const int*)d_in[2];
    // d_in[3] = batch (unused by reference math)
    const float* adj_norm = (const float*)d_in[4];
    const float* root_W   = (const float*)d_in[5];
    const float* root_b   = (const float*)d_in[6];
    const float* rel_W    = (const float*)d_in[7];
    float* out = (float*)d_out;
    float* agg = (float*)d_ws;   // N_NODES * D floats = 25.6 MB

    const int n4 = N_NODES * D / 4;
    zero_kernel<<<(n4 + 255) / 256, 256, 0, stream>>>((float4*)agg, n4);

    const long long tscatter = (long long)N_EDGES * 16;
    scatter_add_kernel<<<(int)((tscatter + 255) / 256), 256, 0, stream>>>(x, row, col, agg);

    fused_out_kernel<<<(N_NODES + 63) / 64, 256, 0, stream>>>(
        x, agg, adj_norm, root_W, root_b, rel_W, out);
}

// Round 2
// 392.306 us; speedup vs baseline: 3.7821x; 3.7821x over previous
//
#include <hip/hip_runtime.h>

#define N_NODES 100000
#define N_EDGES 1600000
#define D 64
#define SCAN_BLK 1024
#define N_SCAN_BLOCKS ((N_NODES + SCAN_BLK - 1) / SCAN_BLK)   // 98

// ---------------------------------------------------------------- utility
__global__ __launch_bounds__(256) void zero_int(int* __restrict__ p, int n) {
    int t = blockIdx.x * 256 + threadIdx.x;
    if (t < n) p[t] = 0;
}

// ---------------------------------------------------------------- degree histogram
__global__ __launch_bounds__(256) void hist_kernel(const int* __restrict__ col,
                                                   int* __restrict__ deg) {
    int e = blockIdx.x * 256 + threadIdx.x;
    if (e < N_EDGES) atomicAdd(&deg[col[e]], 1);
}

// ---------------------------------------------------------------- scan step 1: per-block exclusive scan
__global__ __launch_bounds__(SCAN_BLK) void scan_blocks(const int* __restrict__ deg,
                                                        int* __restrict__ off,
                                                        int* __restrict__ blkSums, int n) {
    int tid = threadIdx.x;
    int gid = blockIdx.x * SCAN_BLK + tid;
    int v = (gid < n) ? deg[gid] : 0;
    int lane = tid & 63, wave = tid >> 6;
    int s = v;
    #pragma unroll
    for (int o = 1; o < 64; o <<= 1) {
        int t = __shfl_up(s, o, 64);
        if (lane >= o) s += t;
    }
    __shared__ int wsum[16];
    if (lane == 63) wsum[wave] = s;
    __syncthreads();
    if (wave == 0 && lane < 16) {
        int ws = wsum[lane];
        #pragma unroll
        for (int o = 1; o < 16; o <<= 1) {
            int t = __shfl_up(ws, o, 64);
            if (lane >= o) ws += t;
        }
        wsum[lane] = ws;
    }
    __syncthreads();
    int wbase = (wave > 0) ? wsum[wave - 1] : 0;
    int incl = s + wbase;
    if (gid < n) off[gid] = incl - v;                 // exclusive
    if (tid == SCAN_BLK - 1) blkSums[blockIdx.x] = incl;
}

// ---------------------------------------------------------------- scan step 2: scan the 98 block sums (1 block)
__global__ __launch_bounds__(128) void scan_sums(int* __restrict__ blkSums, int nb) {
    int tid = threadIdx.x;
    int v = (tid < nb) ? blkSums[tid] : 0;
    int lane = tid & 63, wave = tid >> 6;
    int s = v;
    #pragma unroll
    for (int o = 1; o < 64; o <<= 1) {
        int t = __shfl_up(s, o, 64);
        if (lane >= o) s += t;
    }
    __shared__ int ws2[2];
    if (lane == 63) ws2[wave] = s;
    __syncthreads();
    int incl = s + ((wave > 0) ? ws2[0] : 0);
    if (tid < nb) blkSums[tid] = incl - v;            // exclusive
}

// ---------------------------------------------------------------- scan step 3: add block offsets, init cursors
__global__ __launch_bounds__(SCAN_BLK) void scan_add(int* __restrict__ off,
                                                     int* __restrict__ cursor,
                                                     const int* __restrict__ blkSums, int n) {
    int gid = blockIdx.x * SCAN_BLK + threadIdx.x;
    if (gid < n) {
        int v = off[gid] + blkSums[blockIdx.x];
        off[gid] = v;
        cursor[gid] = v;
    }
}

// ---------------------------------------------------------------- CSR placement
__global__ __launch_bounds__(256) void place_kernel(const int* __restrict__ row,
                                                    const int* __restrict__ col,
                                                    int* __restrict__ cursor,
                                                    int* __restrict__ edge_src) {
    int e = blockIdx.x * 256 + threadIdx.x;
    if (e < N_EDGES) {
        int p = atomicAdd(&cursor[col[e]], 1);
        edge_src[p] = row[e];
    }
}

// ---------------------------------------------------------------- gather aggregation: one wave per node
// lane = feature index; coalesced 256B gathers of x[src]; writes normalized agg once.
__global__ __launch_bounds__(256) void agg_kernel(const float* __restrict__ x,
                                                  const int* __restrict__ edge_src,
                                                  const int* __restrict__ off,
                                                  const int* __restrict__ deg,
                                                  const float* __restrict__ adj_norm,
                                                  float* __restrict__ agg) {
    int w = (blockIdx.x * 256 + threadIdx.x) >> 6;    // node id
    int lane = threadIdx.x & 63;
    if (w >= N_NODES) return;
    int s = off[w];
    int end = s + deg[w];
    float acc = 0.f;
    int i = s;
    for (; i + 4 <= end; i += 4) {
        int s0 = edge_src[i + 0], s1 = edge_src[i + 1];
        int s2 = edge_src[i + 2], s3 = edge_src[i + 3];
        float v0 = x[(size_t)s0 * D + lane];
        float v1 = x[(size_t)s1 * D + lane];
        float v2 = x[(size_t)s2 * D + lane];
        float v3 = x[(size_t)s3 * D + lane];
        acc += v0 + v1 + v2 + v3;
    }
    for (; i < end; ++i) acc += x[(size_t)edge_src[i] * D + lane];
    agg[(size_t)w * D + lane] = acc / adj_norm[w];
}

// ---------------------------------------------------------------- fused dual GEMM + bias + relu
// out[n][j] = relu( sum_d aggn[n][d]*rel_W[j][d] + sum_d x[n][d]*root_W[j][d] + root_b[j] )
#define STRIDE 68

__global__ __launch_bounds__(256) void fused_out_kernel(
    const float* __restrict__ x, const float* __restrict__ agg,
    const float* __restrict__ root_W, const float* __restrict__ root_b,
    const float* __restrict__ rel_W, float* __restrict__ out)
{
    __shared__ float in_sh[64 * STRIDE];
    __shared__ float w_sh[64 * STRIDE];

    const int tid = threadIdx.x;
    const int n0 = blockIdx.x * 64;
    const int jq = tid & 15;
    const int nq = tid >> 4;

    float acc[4][4] = {};

    for (int phase = 0; phase < 2; ++phase) {
        const float* __restrict__ W  = phase ? root_W : rel_W;
        const float* __restrict__ In = phase ? x : agg;

        if (phase) __syncthreads();

        #pragma unroll
        for (int r = 0; r < 4; ++r) {
            int f = r * 256 + tid;
            int j = f >> 4;
            int dq = (f & 15) << 2;
            float4 wv = *reinterpret_cast<const float4*>(W + j * 64 + dq);
            *reinterpret_cast<float4*>(&w_sh[j * STRIDE + dq]) = wv;
        }
        #pragma unroll
        for (int r = 0; r < 4; ++r) {
            int f = r * 256 + tid;
            int n = f >> 4;
            int dq = (f & 15) << 2;
            int gn = n0 + n;
            float4 v = make_float4(0.f, 0.f, 0.f, 0.f);
            if (gn < N_NODES)
                v = *reinterpret_cast<const float4*>(In + (size_t)gn * D + dq);
            *reinterpret_cast<float4*>(&in_sh[n * STRIDE + dq]) = v;
        }
        __syncthreads();

        for (int d = 0; d < 64; d += 4) {
            float4 a[4], w[4];
            #pragma unroll
            for (int i = 0; i < 4; ++i)
                a[i] = *reinterpret_cast<const float4*>(&in_sh[(nq + 16 * i) * STRIDE + d]);
            #pragma unroll
            for (int k = 0; k < 4; ++k)
                w[k] = *reinterpret_cast<const float4*>(&w_sh[(jq + 16 * k) * STRIDE + d]);
            #pragma unroll
            for (int i = 0; i < 4; ++i)
                #pragma unroll
                for (int k = 0; k < 4; ++k)
                    acc[i][k] += a[i].x * w[k].x + a[i].y * w[k].y
                               + a[i].z * w[k].z + a[i].w * w[k].w;
        }
    }

    #pragma unroll
    for (int i = 0; i < 4; ++i) {
        int gn = n0 + nq + 16 * i;
        if (gn >= N_NODES) continue;
        #pragma unroll
        for (int k = 0; k < 4; ++k) {
            int j = jq + 16 * k;
            float v = acc[i][k] + root_b[j];
            out[(size_t)gn * D + j] = fmaxf(v, 0.0f);
        }
    }
}

// ---------------------------------------------------------------- launch
extern "C" void kernel_launch(void* const* d_in, const int* in_sizes, int n_in,
                              void* d_out, int out_size, void* d_ws, size_t ws_size,
                              hipStream_t stream)
{
    const float* x        = (const float*)d_in[0];
    const int*   row      = (const int*)d_in[1];
    const int*   col      = (const int*)d_in[2];
    const float* adj_norm = (const float*)d_in[4];
    const float* root_W   = (const float*)d_in[5];
    const float* root_b   = (const float*)d_in[6];
    const float* rel_W    = (const float*)d_in[7];
    float* out = (float*)d_out;

    // ws layout
    char* ws = (char*)d_ws;
    float* agg      = (float*)ws;                          ws += (size_t)N_NODES * D * 4;   // 25.6 MB
    int*   deg      = (int*)ws;                            ws += (size_t)N_NODES * 4;       // 400 KB
    int*   off      = (int*)ws;                            ws += (size_t)N_NODES * 4;
    int*   cursor   = (int*)ws;                            ws += (size_t)N_NODES * 4;
    int*   blkSums  = (int*)ws;                            ws += 4096;
    int*   edge_src = (int*)ws;                            // 6.4 MB

    zero_int<<<(N_NODES + 255) / 256, 256, 0, stream>>>(deg, N_NODES);
    hist_kernel<<<(N_EDGES + 255) / 256, 256, 0, stream>>>(col, deg);
    scan_blocks<<<N_SCAN_BLOCKS, SCAN_BLK, 0, stream>>>(deg, off, blkSums, N_NODES);
    scan_sums<<<1, 128, 0, stream>>>(blkSums, N_SCAN_BLOCKS);
    scan_add<<<N_SCAN_BLOCKS, SCAN_BLK, 0, stream>>>(off, cursor, blkSums, N_NODES);
    place_kernel<<<(N_EDGES + 255) / 256, 256, 0, stream>>>(row, col, cursor, edge_src);

    const int aggThreads = N_NODES * 64;
    agg_kernel<<<(aggThreads + 255) / 256, 256, 0, stream>>>(x, edge_src, off, deg, adj_norm, agg);

    fused_out_kernel<<<(N_NODES + 63) / 64, 256, 0, stream>>>(
        x, agg, root_W, root_b, rel_W, out);
}